// Round 14
// baseline (90.600 us; speedup 1.0000x reference)
//
#include <hip/hip_runtime.h>

// Segment attention pooling, MI355X (gfx950).
// convw_pack ; segscan ; score_gemm (BM=128 x BN=384, B via global_load_lds
// 3-slot ring + counted vmcnt + raw barriers (m201 pattern), A chunk-dbuf
// staged by role-split waves) ; pool.

#define SEP_ID 102
#define Bn 64
#define Sn 512
#define Hn 768
#define Mn 21
#define BS (Bn * Sn)

typedef __attribute__((ext_vector_type(8))) short bf16x8;
typedef __attribute__((ext_vector_type(8))) unsigned short u16x8;
typedef __attribute__((ext_vector_type(4))) float f32x4;

__device__ inline unsigned short f2bf(float x) {
  unsigned int u = __builtin_bit_cast(unsigned int, x);
  u += 0x7fffu + ((u >> 16) & 1u);   // RNE
  return (unsigned short)(u >> 16);
}

__device__ inline u16x8 cvt8v(f32x4 a, f32x4 b) {
  u16x8 r;
  r[0] = f2bf(a[0]); r[1] = f2bf(a[1]); r[2] = f2bf(a[2]); r[3] = f2bf(a[3]);
  r[4] = f2bf(b[0]); r[5] = f2bf(b[1]); r[6] = f2bf(b[2]); r[7] = f2bf(b[3]);
  return r;
}

__device__ inline float tanh_fast(float x) {
  float e = __builtin_amdgcn_exp2f(x * 2.885390081777927f); // 2*log2(e)
  return 1.f - 2.f * __builtin_amdgcn_rcpf(e + 1.f);
}

// async global->LDS, 16B per lane; LDS dest = wave-uniform base + lane*16
__device__ inline void dma16(const unsigned short* g, unsigned short* l) {
  __builtin_amdgcn_global_load_lds(
      (const __attribute__((address_space(1))) unsigned int*)g,
      (__attribute__((address_space(3))) unsigned int*)l, 16, 0, 0);
}

// ---------------- kernel 1: W fp32 -> bf16, packed in MFMA B-fragment order.
// chunk c = (ntile*24 + kstep)*64 + lane; holds W[ntile*16 + (lane&15)]
// [kstep*32 + (lane>>4)*8 ..+8]
__global__ void convw_kernel(const float* __restrict__ W, unsigned short* __restrict__ WBp) {
  int c = blockIdx.x * 256 + threadIdx.x;   // 73728 chunks, grid 288
  int nt = c / 1536;
  int r  = c % 1536;
  int ks = r >> 6;
  int ln = r & 63;
  int col = nt * 16 + (ln & 15);
  int k0  = ks * 32 + (ln >> 4) * 8;
  const f32x4* src = reinterpret_cast<const f32x4*>(&W[col * Hn + k0]);
  *reinterpret_cast<u16x8*>(&WBp[(size_t)c * 8]) = cvt8v(src[0], src[1]);
}

// ---------------- kernel 2: per-batch segment scan
__global__ void segscan_kernel(const int* __restrict__ ids,
                               unsigned char* __restrict__ segv,
                               int* __restrict__ nsep) {
  int b = blockIdx.x;
  int s = threadIdx.x;
  __shared__ int cs[Sn];
  int sep = (ids[b * Sn + s] == SEP_ID) ? 1 : 0;
  cs[s] = sep;
  __syncthreads();
  for (int off = 1; off < Sn; off <<= 1) {
    int add = (s >= off) ? cs[s - off] : 0;
    __syncthreads();
    cs[s] += add;
    __syncthreads();
  }
  int csum = cs[s];
  int nb = cs[Sn - 1];
  int seg = csum - sep;
  bool valid = (!sep) && (s >= 1) && (seg < nb) && (seg < Mn);
  segv[b * Sn + s] = valid ? (unsigned char)seg : (unsigned char)0xFF;
  if (s == 0) nsep[b] = nb;
}

// ---------------- kernel 3: scores += v . tanh(hidden @ W^T + b)  (N-half)
// Grid 512 = 256 M-tiles x 2 N-halves (pairs placed on same XCD).
// 512 thr = 8 waves: wrow = wid>>2 (M half), wcol = wid&3 (N quarter).
// Wave tile 64 rows x 96 cols -> acc 4x6 f32x4 = 96 AGPR.
// A: [2][128][128] bf16 chunk double-buffer, staged by wrow=1 waves
//    (issue at chunk start, cvt+write after chunk's last MFMA).
// B: global_load_lds DMA into 3-slot ring, issued by wrow=0 waves;
//    per-step raw s_barrier with counted vmcnt(6) (never drain-0 mid-loop).
__global__ __launch_bounds__(512, 2) void score_gemm_kernel(
    const float* __restrict__ hid, const unsigned short* __restrict__ WBp,
    const float* __restrict__ bbias, const float* __restrict__ vvec,
    float* __restrict__ scores) {
  __shared__ __align__(16) unsigned short As[2][128 * 128];   // 2 x 32 KB
  __shared__ __align__(16) unsigned short Bring[3][24 * 512]; // 3 x 24 KB
  __shared__ float scpart[8][64];

  const int t = threadIdx.x;
  const int bid = blockIdx.x;
  const int bq = bid >> 4, br = bid & 15;
  const int mIdx = bq * 8 + (br & 7);   // bid and bid+8 share mIdx AND XCD
  const int nIdx = br >> 3;
  const size_t rowBase = (size_t)mIdx * 128;
  const int wid = t >> 6, lane = t & 63;
  const int l15 = lane & 15, l4 = lane >> 4;
  const int wrow = wid >> 2, wcol = wid & 3;

  // ---- prologue: stage A chunk 0 (all 512 threads: row=t>>2, 32 floats)
  {
    const int row = t >> 2, q4 = t & 3;
    const f32x4* hs = reinterpret_cast<const f32x4*>(
        &hid[(rowBase + row) * Hn + q4 * 32]);
    f32x4 p[8];
#pragma unroll
    for (int j = 0; j < 8; ++j) p[j] = hs[j];
    unsigned short* arow = &As[0][row * 128];
    const int sw = row & 7;
#pragma unroll
    for (int jj = 0; jj < 4; ++jj)
      *reinterpret_cast<u16x8*>(arow + ((q4 * 4 + jj) ^ sw) * 8) =
          cvt8v(p[jj * 2], p[jj * 2 + 1]);
  }
  // wrow0 waves: DMA B slots 0 and 1
  if (wid < 4) {
#pragma unroll
    for (int s = 0; s < 2; ++s)
#pragma unroll
      for (int ni = 0; ni < 6; ++ni) {
        const int ntg = nIdx * 24 + wcol * 6 + ni;
        dma16(&WBp[((size_t)(ntg * 24 + s) * 64 + lane) * 8],
              &Bring[s][(wcol * 6 + ni) * 512]);
      }
  }
  asm volatile("s_waitcnt lgkmcnt(0)" ::: "memory");

  f32x4 acc[4][6];
#pragma unroll
  for (int mi = 0; mi < 4; ++mi)
#pragma unroll
    for (int ni = 0; ni < 6; ++ni) acc[mi][ni] = (f32x4){0.f, 0.f, 0.f, 0.f};

  // wrow1 A-staging coords: 256 threads cover 128 rows x 2 k-halves
  const int tid2 = t & 255;
  const int arow2 = tid2 >> 1, ah = tid2 & 1;
  const int asw2 = arow2 & 7;
  f32x4 ap[16];

#pragma unroll
  for (int kk = 0; kk < 24; ++kk) {
    const int c = kk >> 2, kc = kk & 3, buf = c & 1, slot = kk % 3;
    // (b) writer waves: slot kk complete (counted -- slots kk+1 in flight)
    if (wid < 4) {
      if (kk <= 22) asm volatile("s_waitcnt vmcnt(6)" ::: "memory");
      else          asm volatile("s_waitcnt vmcnt(0)" ::: "memory");
    }
    // (c) rendezvous (no drain for non-writers; A/B prefetch stays in flight)
    __builtin_amdgcn_s_barrier();
    __builtin_amdgcn_sched_barrier(0);
    // (a) post-barrier issues (slot kk+2 memory = slot kk-1, whose readers
    //     retired their ds_reads before arriving at this barrier)
    if (kk + 2 <= 23 && wid < 4) {
      const int s2 = kk + 2, sl2 = s2 % 3;
#pragma unroll
      for (int ni = 0; ni < 6; ++ni) {
        const int ntg = nIdx * 24 + wcol * 6 + ni;
        dma16(&WBp[((size_t)(ntg * 24 + s2) * 64 + lane) * 8],
              &Bring[sl2][(wcol * 6 + ni) * 512]);
      }
    }
    if (kc == 0 && c < 5 && wid >= 4) {
      const f32x4* hs = reinterpret_cast<const f32x4*>(
          &hid[(rowBase + arow2) * Hn + (c + 1) * 128 + ah * 64]);
#pragma unroll
      for (int j = 0; j < 16; ++j) ap[j] = hs[j];
    }
    // (d) fragments + MFMA
    bf16x8 af[4], bfr[6];
#pragma unroll
    for (int mi = 0; mi < 4; ++mi) {
      const int rw = wrow * 64 + mi * 16 + l15;
      af[mi] = *reinterpret_cast<const bf16x8*>(
          &As[buf][rw * 128 + (((kc * 4 + l4) ^ (l15 & 7))) * 8]);
    }
#pragma unroll
    for (int ni = 0; ni < 6; ++ni)
      bfr[ni] = *reinterpret_cast<const bf16x8*>(
          &Bring[slot][(wcol * 6 + ni) * 512 + lane * 8]);
#pragma unroll
    for (int mi = 0; mi < 4; ++mi)
#pragma unroll
      for (int ni = 0; ni < 6; ++ni)
        acc[mi][ni] = __builtin_amdgcn_mfma_f32_16x16x32_bf16(
            af[mi], bfr[ni], acc[mi][ni], 0, 0, 0);
    // (e) chunk end: wrow1 converts + writes next A chunk (write-late, T14)
    if (kc == 3 && c < 5 && wid >= 4) {
      unsigned short* arow = &As[buf ^ 1][arow2 * 128];
#pragma unroll
      for (int jj = 0; jj < 8; ++jj)
        *reinterpret_cast<u16x8*>(arow + ((ah * 8 + jj) ^ asw2) * 8) =
            cvt8v(ap[jj * 2], ap[jj * 2 + 1]);
      asm volatile("s_waitcnt lgkmcnt(0)" ::: "memory");
    }
  }

  // ---- fused epilogue: tanh(pre + b) * v over the wave's 96 cols
  float sc[4][4];
#pragma unroll
  for (int mi = 0; mi < 4; ++mi)
#pragma unroll
    for (int r = 0; r < 4; ++r) sc[mi][r] = 0.f;
#pragma unroll
  for (int ni = 0; ni < 6; ++ni) {
    const int col = nIdx * 384 + wcol * 96 + ni * 16 + l15;
    const float vv = vvec[col];
    const float bb = bbias[col];
#pragma unroll
    for (int mi = 0; mi < 4; ++mi)
#pragma unroll
      for (int r = 0; r < 4; ++r)
        sc[mi][r] += tanh_fast(acc[mi][ni][r] + bb) * vv;
  }
#pragma unroll
  for (int off = 1; off < 16; off <<= 1)
#pragma unroll
    for (int mi = 0; mi < 4; ++mi)
#pragma unroll
      for (int r = 0; r < 4; ++r)
        sc[mi][r] += __shfl_xor(sc[mi][r], off, 64);
  if (l15 == 0) {
#pragma unroll
    for (int mi = 0; mi < 4; ++mi)
#pragma unroll
      for (int r = 0; r < 4; ++r)
        scpart[wid][mi * 16 + l4 * 4 + r] = sc[mi][r];
  }
  __syncthreads();
  if (t < 128) {
    float s = 0.f;
#pragma unroll
    for (int wc = 0; wc < 4; ++wc) s += scpart[(t >> 6) * 4 + wc][t & 63];
    atomicAdd(&scores[rowBase + t], s);
  }
}

// ---------------- kernel 4: per-(b,m) segment softmax + pooling
__global__ __launch_bounds__(256) void pool_kernel(
    const float* __restrict__ hid, const float* __restrict__ scores,
    const unsigned char* __restrict__ segv, const int* __restrict__ nsep,
    float* __restrict__ out) {
  int bm = blockIdx.x;
  int b = bm / Mn, m = bm % Mn;
  int t = threadIdx.x;
  __shared__ float wLds[Sn];
  __shared__ float red[256];
  __shared__ int ired[256];
  const float NEG = -1e30f;

  int base = b * Sn;
  unsigned char mg = (unsigned char)m;
  unsigned char g0 = segv[base + t], g1 = segv[base + 256 + t];
  bool v0 = (g0 == mg), v1 = (g1 == mg);
  float s0 = v0 ? scores[base + t] : NEG;
  float s1 = v1 ? scores[base + 256 + t] : NEG;

  red[t] = fmaxf(s0, s1);
  __syncthreads();
  for (int o = 128; o > 0; o >>= 1) {
    if (t < o) red[t] = fmaxf(red[t], red[t + o]);
    __syncthreads();
  }
  float gmax = red[0];
  __syncthreads();

  size_t obase = (size_t)bm * Hn;
  if (gmax <= -0.5e30f) {
    int nb = nsep[b];
    float a0 = 0.f, a1 = 0.f, a2 = 0.f;
    if (m == 0 && nb == 0) {
      const float* hp = hid + (size_t)base * Hn;
      a0 = hp[t]; a1 = hp[t + 256]; a2 = hp[t + 512];
    }
    out[obase + t] = a0; out[obase + 256 + t] = a1; out[obase + 512 + t] = a2;
    return;
  }

  float e0 = v0 ? expf(s0 - gmax) : 0.f;
  float e1 = v1 ? expf(s1 - gmax) : 0.f;
  red[t] = e0 + e1;
  __syncthreads();
  for (int o = 128; o > 0; o >>= 1) {
    if (t < o) red[t] += red[t + o];
    __syncthreads();
  }
  float inv = 1.f / red[0];
  __syncthreads();
  wLds[t] = e0 * inv;
  wLds[256 + t] = e1 * inv;

  ired[t] = min(v0 ? t : 0x7fffffff, v1 ? (256 + t) : 0x7fffffff);
  __syncthreads();
  for (int o = 128; o > 0; o >>= 1) {
    if (t < o) ired[t] = min(ired[t], ired[t + o]);
    __syncthreads();
  }
  int start = ired[0];
  __syncthreads();
  ired[t] = max(v0 ? t : -1, v1 ? (256 + t) : -1);
  __syncthreads();
  for (int o = 128; o > 0; o >>= 1) {
    if (t < o) ired[t] = max(ired[t], ired[t + o]);
    __syncthreads();
  }
  int end = ired[0];
  __syncthreads();

  float a0 = 0.f, a1 = 0.f, a2 = 0.f;
  for (int s = start; s <= end; ++s) {
    float w = wLds[s];
    if (w != 0.f) {
      const float* hp = hid + (size_t)(base + s) * Hn;
      a0 += w * hp[t];
      a1 += w * hp[t + 256];
      a2 += w * hp[t + 512];
    }
  }
  out[obase + t] = a0;
  out[obase + 256 + t] = a1;
  out[obase + 512 + t] = a2;
}

// ---------------- launch
extern "C" void kernel_launch(void* const* d_in, const int* in_sizes, int n_in,
                              void* d_out, int out_size, void* d_ws, size_t ws_size,
                              hipStream_t stream) {
  const float* hidden = (const float*)d_in[0];
  const int* ids      = (const int*)d_in[1];
  const float* W      = (const float*)d_in[2];
  const float* bbias  = (const float*)d_in[3];
  const float* vvec   = (const float*)d_in[4];

  char* ws = (char*)d_ws;
  unsigned short* WBp  = (unsigned short*)(ws);            // 1,179,648 B
  float* scores        = (float*)(ws + 1179648);           //   131,072 B
  unsigned char* segv  = (unsigned char*)(ws + 1310720);
  int* nsep            = (int*)(ws + 1343488);

  convw_kernel<<<288, 256, 0, stream>>>(W, WBp);
  segscan_kernel<<<Bn, Sn, 0, stream>>>(ids, segv, nsep);
  hipMemsetAsync(scores, 0, BS * sizeof(float), stream);
  score_gemm_kernel<<<512, 512, 0, stream>>>(hidden, WBp, bbias, vvec, scores);
  pool_kernel<<<Bn * Mn, 256, 0, stream>>>(hidden, scores, segv, nsep, (float*)d_out);
}

// Round 15
// 86.561 us; speedup vs baseline: 1.0467x; 1.0467x over previous
//
#include <hip/hip_runtime.h>

// Segment attention pooling, MI355X (gfx950).
// convw_pack (fp32 W -> bf16, MFMA-fragment order) ; segscan ;
// score_gemm (BM=32, TWO independent blocks/CU: 48KB LDS + <=128 regs/wave,
// barrier-free K-loop, 8 waves of 32x96) ; pool.

#define SEP_ID 102
#define Bn 64
#define Sn 512
#define Hn 768
#define Mn 21
#define BS (Bn * Sn)

typedef __attribute__((ext_vector_type(8))) short bf16x8;
typedef __attribute__((ext_vector_type(8))) unsigned short u16x8;
typedef __attribute__((ext_vector_type(4))) float f32x4;

__device__ inline unsigned short f2bf(float x) {
  unsigned int u = __builtin_bit_cast(unsigned int, x);
  u += 0x7fffu + ((u >> 16) & 1u);   // RNE
  return (unsigned short)(u >> 16);
}

__device__ inline u16x8 cvt8v(f32x4 a, f32x4 b) {
  u16x8 r;
  r[0] = f2bf(a[0]); r[1] = f2bf(a[1]); r[2] = f2bf(a[2]); r[3] = f2bf(a[3]);
  r[4] = f2bf(b[0]); r[5] = f2bf(b[1]); r[6] = f2bf(b[2]); r[7] = f2bf(b[3]);
  return r;
}

__device__ inline float tanh_fast(float x) {
  float e = __builtin_amdgcn_exp2f(x * 2.885390081777927f); // 2*log2(e)
  return 1.f - 2.f * __builtin_amdgcn_rcpf(e + 1.f);
}

// ---------------- kernel 1: W fp32 -> bf16, packed in MFMA B-fragment order.
// chunk c = (ntile*24 + kstep)*64 + lane; holds W[ntile*16 + (lane&15)]
// [kstep*32 + (lane>>4)*8 ..+8]  -> score_gemm B loads are lane-contiguous.
__global__ void convw_kernel(const float* __restrict__ W, unsigned short* __restrict__ WBp) {
  int c = blockIdx.x * 256 + threadIdx.x;   // 73728 chunks, grid 288
  int nt = c / 1536;
  int r  = c % 1536;
  int ks = r >> 6;
  int ln = r & 63;
  int col = nt * 16 + (ln & 15);
  int k0  = ks * 32 + (ln >> 4) * 8;
  const f32x4* src = reinterpret_cast<const f32x4*>(&W[col * Hn + k0]);
  *reinterpret_cast<u16x8*>(&WBp[(size_t)c * 8]) = cvt8v(src[0], src[1]);
}

// ---------------- kernel 2: per-batch segment scan
__global__ void segscan_kernel(const int* __restrict__ ids,
                               unsigned char* __restrict__ segv,
                               int* __restrict__ nsep) {
  int b = blockIdx.x;
  int s = threadIdx.x;
  __shared__ int cs[Sn];
  int sep = (ids[b * Sn + s] == SEP_ID) ? 1 : 0;
  cs[s] = sep;
  __syncthreads();
  for (int off = 1; off < Sn; off <<= 1) {
    int add = (s >= off) ? cs[s - off] : 0;
    __syncthreads();
    cs[s] += add;
    __syncthreads();
  }
  int csum = cs[s];
  int nb = cs[Sn - 1];
  int seg = csum - sep;
  bool valid = (!sep) && (s >= 1) && (seg < nb) && (seg < Mn);
  segv[b * Sn + s] = valid ? (unsigned char)seg : (unsigned char)0xFF;
  if (s == 0) nsep[b] = nb;
}

// ---------------- kernel 3: scores = v . tanh(hidden @ W^T + b)
// 512 thr = 8 waves, block = 32 rows x 768 cols, wave = 32 rows x 96 cols.
// acc 2x6 f32x4 = 48 AGPR; ~110 unified regs/wave; LDS 50 KB
// -> TWO independent blocks per CU (16 waves/CU), phases naturally offset:
// one block's HBM staging overlaps the other's MFMA/L2 K-loop.
// Prologue: stage 32x768 A-tile (fp32->bf16) in LDS, one barrier.
// K-loop: 24 steps, NO barriers, plain per-step loads (compiler pipelines).
__global__ __launch_bounds__(512, 4) void score_gemm_kernel(
    const float* __restrict__ hid, const unsigned short* __restrict__ WBp,
    const float* __restrict__ bbias, const float* __restrict__ vvec,
    float* __restrict__ scores) {
  __shared__ __align__(16) unsigned short As[32 * 768];   // 49152 B
  __shared__ float scpart[8][32];

  const int t = threadIdx.x;
  const size_t rowBase = (size_t)blockIdx.x * 32;
  const int wid = t >> 6, lane = t & 63;
  const int l15 = lane & 15, l4 = lane >> 4;
  const int colBase = wid * 96;

  // ---- prologue: stage A (row = t>>4 in 0..31, 16B chunk scloc = t&15,
  // one chunk per each of the 6 K-chunks of 128). XOR-swizzle chunk ^ (row&7).
  {
    const int srow = t >> 4;
    const int scloc = t & 15;
    const f32x4* hsrc = reinterpret_cast<const f32x4*>(
        &hid[(rowBase + srow) * Hn + scloc * 8]);   // f32x4 units
    unsigned short* const arow = &As[srow * Hn];
    const int swz = srow & 7;
    f32x4 p[6][2];
#pragma unroll
    for (int cc = 0; cc < 6; ++cc) {
      p[cc][0] = hsrc[cc * 32];
      p[cc][1] = hsrc[cc * 32 + 1];
    }
#pragma unroll
    for (int cc = 0; cc < 6; ++cc)
      *reinterpret_cast<u16x8*>(arow + ((cc * 16 + scloc) ^ swz) * 8) =
          cvt8v(p[cc][0], p[cc][1]);
  }
  __syncthreads();

  // A frag read base: row = mi*16 + l15, chunk = (kk*4 + l4) ^ (l15&7)
  const unsigned short* const afrow = &As[l15 * Hn];
  const int aswz = l15 & 7;
  // B: packed fragment chunks, ntile = wid*6 + ni, per-kstep stride 512 shorts
  const unsigned short* bp[6];
#pragma unroll
  for (int ni = 0; ni < 6; ++ni)
    bp[ni] = &WBp[((size_t)(wid * 6 + ni) * 24 * 64 + lane) * 8];

  f32x4 acc[2][6];
#pragma unroll
  for (int mi = 0; mi < 2; ++mi)
#pragma unroll
    for (int ni = 0; ni < 6; ++ni) acc[mi][ni] = (f32x4){0.f, 0.f, 0.f, 0.f};

#pragma unroll
  for (int kk = 0; kk < 24; ++kk) {
    bf16x8 af[2];
#pragma unroll
    for (int mi = 0; mi < 2; ++mi)
      af[mi] = *reinterpret_cast<const bf16x8*>(
          &afrow[mi * 16 * Hn + (((kk * 4 + l4) ^ aswz)) * 8]);
    bf16x8 br[6];
#pragma unroll
    for (int ni = 0; ni < 6; ++ni)
      br[ni] = *reinterpret_cast<const bf16x8*>(bp[ni] + kk * 512);
#pragma unroll
    for (int mi = 0; mi < 2; ++mi)
#pragma unroll
      for (int ni = 0; ni < 6; ++ni)
        acc[mi][ni] = __builtin_amdgcn_mfma_f32_16x16x32_bf16(
            af[mi], br[ni], acc[mi][ni], 0, 0, 0);
  }

  // ---- fused epilogue: tanh(pre + b) * v over the wave's 96 cols
  float sc[2][4];
#pragma unroll
  for (int mi = 0; mi < 2; ++mi)
#pragma unroll
    for (int r = 0; r < 4; ++r) sc[mi][r] = 0.f;
#pragma unroll
  for (int ni = 0; ni < 6; ++ni) {
    int col = colBase + ni * 16 + l15;
    float vv = vvec[col];
    float bb = bbias[col];
#pragma unroll
    for (int mi = 0; mi < 2; ++mi)
#pragma unroll
      for (int r = 0; r < 4; ++r)
        sc[mi][r] += tanh_fast(acc[mi][ni][r] + bb) * vv;
  }
#pragma unroll
  for (int off = 1; off < 16; off <<= 1)
#pragma unroll
    for (int mi = 0; mi < 2; ++mi)
#pragma unroll
      for (int r = 0; r < 4; ++r)
        sc[mi][r] += __shfl_xor(sc[mi][r], off, 64);
  if (l15 == 0) {
#pragma unroll
    for (int mi = 0; mi < 2; ++mi)
#pragma unroll
      for (int r = 0; r < 4; ++r)
        scpart[wid][mi * 16 + l4 * 4 + r] = sc[mi][r];
  }
  __syncthreads();
  if (t < 32) {
    float s = 0.f;
#pragma unroll
    for (int w = 0; w < 8; ++w) s += scpart[w][t];
    scores[rowBase + t] = s;
  }
}

// ---------------- kernel 4: per-(b,m) segment softmax + pooling
__global__ __launch_bounds__(256) void pool_kernel(
    const float* __restrict__ hid, const float* __restrict__ scores,
    const unsigned char* __restrict__ segv, const int* __restrict__ nsep,
    float* __restrict__ out) {
  int bm = blockIdx.x;
  int b = bm / Mn, m = bm % Mn;
  int t = threadIdx.x;
  __shared__ float wLds[Sn];
  __shared__ float red[256];
  __shared__ int ired[256];
  const float NEG = -1e30f;

  int base = b * Sn;
  unsigned char mg = (unsigned char)m;
  unsigned char g0 = segv[base + t], g1 = segv[base + 256 + t];
  bool v0 = (g0 == mg), v1 = (g1 == mg);
  float s0 = v0 ? scores[base + t] : NEG;
  float s1 = v1 ? scores[base + 256 + t] : NEG;

  red[t] = fmaxf(s0, s1);
  __syncthreads();
  for (int o = 128; o > 0; o >>= 1) {
    if (t < o) red[t] = fmaxf(red[t], red[t + o]);
    __syncthreads();
  }
  float gmax = red[0];
  __syncthreads();

  size_t obase = (size_t)bm * Hn;
  if (gmax <= -0.5e30f) {
    int nb = nsep[b];
    float a0 = 0.f, a1 = 0.f, a2 = 0.f;
    if (m == 0 && nb == 0) {
      const float* hp = hid + (size_t)base * Hn;
      a0 = hp[t]; a1 = hp[t + 256]; a2 = hp[t + 512];
    }
    out[obase + t] = a0; out[obase + 256 + t] = a1; out[obase + 512 + t] = a2;
    return;
  }

  float e0 = v0 ? expf(s0 - gmax) : 0.f;
  float e1 = v1 ? expf(s1 - gmax) : 0.f;
  red[t] = e0 + e1;
  __syncthreads();
  for (int o = 128; o > 0; o >>= 1) {
    if (t < o) red[t] += red[t + o];
    __syncthreads();
  }
  float inv = 1.f / red[0];
  __syncthreads();
  wLds[t] = e0 * inv;
  wLds[256 + t] = e1 * inv;

  ired[t] = min(v0 ? t : 0x7fffffff, v1 ? (256 + t) : 0x7fffffff);
  __syncthreads();
  for (int o = 128; o > 0; o >>= 1) {
    if (t < o) ired[t] = min(ired[t], ired[t + o]);
    __syncthreads();
  }
  int start = ired[0];
  __syncthreads();
  ired[t] = max(v0 ? t : -1, v1 ? (256 + t) : -1);
  __syncthreads();
  for (int o = 128; o > 0; o >>= 1) {
    if (t < o) ired[t] = max(ired[t], ired[t + o]);
    __syncthreads();
  }
  int end = ired[0];
  __syncthreads();

  float a0 = 0.f, a1 = 0.f, a2 = 0.f;
  for (int s = start; s <= end; ++s) {
    float w = wLds[s];
    if (w != 0.f) {
      const float* hp = hid + (size_t)(base + s) * Hn;
      a0 += w * hp[t];
      a1 += w * hp[t + 256];
      a2 += w * hp[t + 512];
    }
  }
  out[obase + t] = a0;
  out[obase + 256 + t] = a1;
  out[obase + 512 + t] = a2;
}

// ---------------- launch
extern "C" void kernel_launch(void* const* d_in, const int* in_sizes, int n_in,
                              void* d_out, int out_size, void* d_ws, size_t ws_size,
                              hipStream_t stream) {
  const float* hidden = (const float*)d_in[0];
  const int* ids      = (const int*)d_in[1];
  const float* W      = (const float*)d_in[2];
  const float* bbias  = (const float*)d_in[3];
  const float* vvec   = (const float*)d_in[4];

  char* ws = (char*)d_ws;
  unsigned short* WBp  = (unsigned short*)(ws);            // 1,179,648 B
  float* scores        = (float*)(ws + 1179648);
  unsigned char* segv  = (unsigned char*)(ws + 1310720);
  int* nsep            = (int*)(ws + 1343488);

  convw_kernel<<<288, 256, 0, stream>>>(W, WBp);
  segscan_kernel<<<Bn, Sn, 0, stream>>>(ids, segv, nsep);
  score_gemm_kernel<<<BS / 32, 512, 0, stream>>>(hidden, WBp, bbias, vvec, scores);
  pool_kernel<<<Bn * Mn, 256, 0, stream>>>(hidden, scores, segv, nsep, (float*)d_out);
}

// Round 16
// 75.784 us; speedup vs baseline: 1.1955x; 1.1422x over previous
//
#include <hip/hip_runtime.h>

// Segment attention pooling, MI355X (gfx950).  [RESTORE: round-13 best]
// convw_pack (fp32 W -> bf16, MFMA-fragment order) ; segscan ;
// score_gemm (whole A-tile LDS-resident, barrier-free K-loop,
// 8 FAT waves (64x96, 256-reg budget), A-frag dbuf + depth-2 B ring) ; pool.

#define SEP_ID 102
#define Bn 64
#define Sn 512
#define Hn 768
#define Mn 21
#define BS (Bn * Sn)

typedef __attribute__((ext_vector_type(8))) short bf16x8;
typedef __attribute__((ext_vector_type(8))) unsigned short u16x8;
typedef __attribute__((ext_vector_type(4))) float f32x4;

__device__ inline unsigned short f2bf(float x) {
  unsigned int u = __builtin_bit_cast(unsigned int, x);
  u += 0x7fffu + ((u >> 16) & 1u);   // RNE
  return (unsigned short)(u >> 16);
}

__device__ inline u16x8 cvt8v(f32x4 a, f32x4 b) {
  u16x8 r;
  r[0] = f2bf(a[0]); r[1] = f2bf(a[1]); r[2] = f2bf(a[2]); r[3] = f2bf(a[3]);
  r[4] = f2bf(b[0]); r[5] = f2bf(b[1]); r[6] = f2bf(b[2]); r[7] = f2bf(b[3]);
  return r;
}

__device__ inline float tanh_fast(float x) {
  float e = __builtin_amdgcn_exp2f(x * 2.885390081777927f); // 2*log2(e)
  return 1.f - 2.f * __builtin_amdgcn_rcpf(e + 1.f);
}

// ---------------- kernel 1: W fp32 -> bf16, packed in MFMA B-fragment order.
// chunk c = (ntile*24 + kstep)*64 + lane; holds W[ntile*16 + (lane&15)]
// [kstep*32 + (lane>>4)*8 ..+8]  -> score_gemm B loads are lane-contiguous.
__global__ void convw_kernel(const float* __restrict__ W, unsigned short* __restrict__ WBp) {
  int c = blockIdx.x * 256 + threadIdx.x;   // 73728 chunks, grid 288
  int nt = c / 1536;
  int r  = c % 1536;
  int ks = r >> 6;
  int ln = r & 63;
  int col = nt * 16 + (ln & 15);
  int k0  = ks * 32 + (ln >> 4) * 8;
  const f32x4* src = reinterpret_cast<const f32x4*>(&W[col * Hn + k0]);
  f32x4 a = src[0];
  f32x4 b = src[1];
  *reinterpret_cast<u16x8*>(&WBp[(size_t)c * 8]) = cvt8v(a, b);
}

// ---------------- kernel 2: per-batch segment scan
__global__ void segscan_kernel(const int* __restrict__ ids,
                               unsigned char* __restrict__ segv,
                               int* __restrict__ nsep) {
  int b = blockIdx.x;
  int s = threadIdx.x;
  __shared__ int cs[Sn];
  int sep = (ids[b * Sn + s] == SEP_ID) ? 1 : 0;
  cs[s] = sep;
  __syncthreads();
  for (int off = 1; off < Sn; off <<= 1) {
    int add = (s >= off) ? cs[s - off] : 0;
    __syncthreads();
    cs[s] += add;
    __syncthreads();
  }
  int csum = cs[s];
  int nb = cs[Sn - 1];
  int seg = csum - sep;
  bool valid = (!sep) && (s >= 1) && (seg < nb) && (seg < Mn);
  segv[b * Sn + s] = valid ? (unsigned char)seg : (unsigned char)0xFF;
  if (s == 0) nsep[b] = nb;
}

// ---------------- kernel 3: scores = v . tanh(hidden @ W^T + b)
// 512 thr = 8 waves, block = 64 rows x 768 cols, wave = 64 rows x 96 cols.
// __launch_bounds__(512,2) -> 256 regs/wave: acc 96 AGPR + A dbuf 32 +
// depth-2 B ring 96 VGPR fit WITHOUT spilling.
// Prologue: stage whole 64x768 A-tile (fp32->bf16) into LDS, one barrier.
// K-loop: 24 steps, NO barriers (A read-only; waves free-run).
__global__ __launch_bounds__(512, 2) void score_gemm_kernel(
    const float* __restrict__ hid, const unsigned short* __restrict__ WBp,
    const float* __restrict__ bbias, const float* __restrict__ vvec,
    float* __restrict__ scores) {
  __shared__ __align__(16) unsigned short As[64 * 768];   // 98304 B
  __shared__ float scpart[8][64];

  const int t = threadIdx.x;
  const size_t rowBase = (size_t)blockIdx.x * 64;
  const int wid = t >> 6, lane = t & 63;
  const int l15 = lane & 15, l4 = lane >> 4;
  const int colBase = wid * 96;

  // ---- prologue: stage A. Thread t: row = t>>3, chunk set c = (t&7) + 8j,
  // j = 0..11 (96 chunks of 16B per row). XOR-swizzle chunk ^ (row&7) stays
  // within each aligned-8 chunk group: (sq+8j)^swz = (sq^swz)+8j.
  {
    const int srow = t >> 3;
    const int sq = t & 7;
    const f32x4* hsrc = reinterpret_cast<const f32x4*>(
        &hid[(rowBase + srow) * Hn + sq * 8]);      // f32x4 units, +2 per chunk
    unsigned short* const arow = &As[srow * Hn];
    const int wq = (sq ^ (srow & 7));
    f32x4 p[12][2];
#pragma unroll
    for (int j = 0; j < 12; ++j) {
      p[j][0] = hsrc[j * 16];
      p[j][1] = hsrc[j * 16 + 1];
    }
#pragma unroll
    for (int j = 0; j < 12; ++j)
      *reinterpret_cast<u16x8*>(arow + (wq + 8 * j) * 8) = cvt8v(p[j][0], p[j][1]);
  }
  __syncthreads();

  // A frag read base: row = mi*16 + l15, chunk = (kk*4 + l4) ^ (l15&7)
  const unsigned short* const afrow = &As[l15 * Hn];
  const int aswz = l15 & 7;
  // B: packed fragment chunks, ntile = wid*6 + ni, per-kstep stride 512 shorts
  const unsigned short* bp[6];
#pragma unroll
  for (int ni = 0; ni < 6; ++ni)
    bp[ni] = &WBp[((size_t)(wid * 6 + ni) * 24 * 64 + lane) * 8];

  f32x4 acc[4][6];
#pragma unroll
  for (int mi = 0; mi < 4; ++mi)
#pragma unroll
    for (int ni = 0; ni < 6; ++ni) acc[mi][ni] = (f32x4){0.f, 0.f, 0.f, 0.f};

  // double buffers: afA/afB (A frags), brA/brB (B frags, 6 each)
  bf16x8 afA[4], afB[4], brA[6], brB[6];
#pragma unroll
  for (int mi = 0; mi < 4; ++mi)
    afA[mi] = *reinterpret_cast<const bf16x8*>(
        &afrow[mi * 16 * Hn + ((l4 ^ aswz)) * 8]);          // kk = 0
#pragma unroll
  for (int ni = 0; ni < 6; ++ni)
    brA[ni] = *reinterpret_cast<const bf16x8*>(bp[ni]);

  // one pipeline step: load (kk+1) into afn/brn, then 24 MFMA on afc/brc
#define STEP(kk_, afc, afn, brc, brn)                                       \
  {                                                                         \
    if ((kk_) < 23) {                                                       \
      _Pragma("unroll")                                                     \
      for (int mi = 0; mi < 4; ++mi)                                        \
        afn[mi] = *reinterpret_cast<const bf16x8*>(                         \
            &afrow[mi * 16 * Hn + ((((kk_) + 1) * 4 + l4) ^ aswz) * 8]);    \
      _Pragma("unroll")                                                     \
      for (int ni = 0; ni < 6; ++ni)                                        \
        brn[ni] = *reinterpret_cast<const bf16x8*>(bp[ni] + ((kk_) + 1) * 512); \
    }                                                                       \
    __builtin_amdgcn_sched_barrier(0);                                      \
    _Pragma("unroll")                                                       \
    for (int mi = 0; mi < 4; ++mi)                                          \
      _Pragma("unroll")                                                     \
      for (int ni = 0; ni < 6; ++ni)                                        \
        acc[mi][ni] = __builtin_amdgcn_mfma_f32_16x16x32_bf16(              \
            afc[mi], brc[ni], acc[mi][ni], 0, 0, 0);                        \
  }

#pragma unroll
  for (int k2 = 0; k2 < 12; ++k2) {
    STEP(k2 * 2,     afA, afB, brA, brB)
    STEP(k2 * 2 + 1, afB, afA, brB, brA)
  }
#undef STEP

  // ---- fused epilogue: tanh(pre + b) * v over the wave's 96 cols
  float sc[4][4];
#pragma unroll
  for (int mi = 0; mi < 4; ++mi)
#pragma unroll
    for (int r = 0; r < 4; ++r) sc[mi][r] = 0.f;
#pragma unroll
  for (int ni = 0; ni < 6; ++ni) {
    int col = colBase + ni * 16 + l15;
    float vv = vvec[col];
    float bb = bbias[col];
#pragma unroll
    for (int mi = 0; mi < 4; ++mi)
#pragma unroll
      for (int r = 0; r < 4; ++r)
        sc[mi][r] += tanh_fast(acc[mi][ni][r] + bb) * vv;
  }
#pragma unroll
  for (int off = 1; off < 16; off <<= 1)
#pragma unroll
    for (int mi = 0; mi < 4; ++mi)
#pragma unroll
      for (int r = 0; r < 4; ++r)
        sc[mi][r] += __shfl_xor(sc[mi][r], off, 64);
  if (l15 == 0) {
#pragma unroll
    for (int mi = 0; mi < 4; ++mi)
#pragma unroll
      for (int r = 0; r < 4; ++r)
        scpart[wid][mi * 16 + l4 * 4 + r] = sc[mi][r];
  }
  __syncthreads();
  if (t < 64) {
    float s = 0.f;
#pragma unroll
    for (int w = 0; w < 8; ++w) s += scpart[w][t];
    scores[rowBase + t] = s;
  }
}

// ---------------- kernel 4: per-(b,m) segment softmax + pooling
__global__ __launch_bounds__(256) void pool_kernel(
    const float* __restrict__ hid, const float* __restrict__ scores,
    const unsigned char* __restrict__ segv, const int* __restrict__ nsep,
    float* __restrict__ out) {
  int bm = blockIdx.x;
  int b = bm / Mn, m = bm % Mn;
  int t = threadIdx.x;
  __shared__ float wLds[Sn];
  __shared__ float red[256];
  __shared__ int ired[256];
  const float NEG = -1e30f;

  int base = b * Sn;
  unsigned char mg = (unsigned char)m;
  unsigned char g0 = segv[base + t], g1 = segv[base + 256 + t];
  bool v0 = (g0 == mg), v1 = (g1 == mg);
  float s0 = v0 ? scores[base + t] : NEG;
  float s1 = v1 ? scores[base + 256 + t] : NEG;

  red[t] = fmaxf(s0, s1);
  __syncthreads();
  for (int o = 128; o > 0; o >>= 1) {
    if (t < o) red[t] = fmaxf(red[t], red[t + o]);
    __syncthreads();
  }
  float gmax = red[0];
  __syncthreads();

  size_t obase = (size_t)bm * Hn;
  if (gmax <= -0.5e30f) {
    int nb = nsep[b];
    float a0 = 0.f, a1 = 0.f, a2 = 0.f;
    if (m == 0 && nb == 0) {
      const float* hp = hid + (size_t)base * Hn;
      a0 = hp[t]; a1 = hp[t + 256]; a2 = hp[t + 512];
    }
    out[obase + t] = a0; out[obase + 256 + t] = a1; out[obase + 512 + t] = a2;
    return;
  }

  float e0 = v0 ? expf(s0 - gmax) : 0.f;
  float e1 = v1 ? expf(s1 - gmax) : 0.f;
  red[t] = e0 + e1;
  __syncthreads();
  for (int o = 128; o > 0; o >>= 1) {
    if (t < o) red[t] += red[t + o];
    __syncthreads();
  }
  float inv = 1.f / red[0];
  __syncthreads();
  wLds[t] = e0 * inv;
  wLds[256 + t] = e1 * inv;

  ired[t] = min(v0 ? t : 0x7fffffff, v1 ? (256 + t) : 0x7fffffff);
  __syncthreads();
  for (int o = 128; o > 0; o >>= 1) {
    if (t < o) ired[t] = min(ired[t], ired[t + o]);
    __syncthreads();
  }
  int start = ired[0];
  __syncthreads();
  ired[t] = max(v0 ? t : -1, v1 ? (256 + t) : -1);
  __syncthreads();
  for (int o = 128; o > 0; o >>= 1) {
    if (t < o) ired[t] = max(ired[t], ired[t + o]);
    __syncthreads();
  }
  int end = ired[0];
  __syncthreads();

  float a0 = 0.f, a1 = 0.f, a2 = 0.f;
  for (int s = start; s <= end; ++s) {
    float w = wLds[s];
    if (w != 0.f) {
      const float* hp = hid + (size_t)(base + s) * Hn;
      a0 += w * hp[t];
      a1 += w * hp[t + 256];
      a2 += w * hp[t + 512];
    }
  }
  out[obase + t] = a0;
  out[obase + 256 + t] = a1;
  out[obase + 512 + t] = a2;
}

// ---------------- launch
extern "C" void kernel_launch(void* const* d_in, const int* in_sizes, int n_in,
                              void* d_out, int out_size, void* d_ws, size_t ws_size,
                              hipStream_t stream) {
  const float* hidden = (const float*)d_in[0];
  const int* ids      = (const int*)d_in[1];
  const float* W      = (const float*)d_in[2];
  const float* bbias  = (const float*)d_in[3];
  const float* vvec   = (const float*)d_in[4];

  char* ws = (char*)d_ws;
  unsigned short* WBp  = (unsigned short*)(ws);            // 1,179,648 B
  float* scores        = (float*)(ws + 1179648);
  unsigned char* segv  = (unsigned char*)(ws + 1310720);
  int* nsep            = (int*)(ws + 1343488);

  convw_kernel<<<288, 256, 0, stream>>>(W, WBp);
  segscan_kernel<<<Bn, Sn, 0, stream>>>(ids, segv, nsep);
  score_gemm_kernel<<<BS / 64, 512, 0, stream>>>(hidden, WBp, bbias, vvec, scores);
  pool_kernel<<<Bn * Mn, 256, 0, stream>>>(hidden, scores, segv, nsep, (float*)d_out);
}